// Round 4
// baseline (10666.248 us; speedup 1.0000x reference)
//
#include <hip/hip_runtime.h>
#include <hip/hip_fp16.h>
#include <cmath>

typedef _Float16 f16;
typedef _Float16 half8 __attribute__((ext_vector_type(8)));
typedef float f32x4 __attribute__((ext_vector_type(4)));

#define P_WG   75          // workgroups per direction
#define NKT    30          // K tiles of 32: 10 x-part (K=320 pad of 300) + 20 h-part (K=640 pad of 600)
#define GRID_MAIN (2*P_WG) // 150

#define X16_ELEMS  (64u*512u*320u)            // 10,485,760 f16 per plane
#define BPK_HALF   (2u*75u*2u*30u*64u*8u)     // 4,608,000 f16 (one term plane)
#define HBUF_F16   (2u*2u*2u*64u*640u)        // dirs*bufs*planes*rows*cols = 655,360 f16
#define HBUF_WORDS (HBUF_F16/2u)              // 327,680 u32
#define FLAG_WORDS 256u                       // 2 dirs x 128 u32 (75 used + pad)

// ---------------- prep: rebuild all workspace state every launch ----------------
__global__ void lstm_prep(const float* __restrict__ x,
                          const float* __restrict__ Wf, const float* __restrict__ Uf,
                          const float* __restrict__ Wb, const float* __restrict__ Ub,
                          const int* __restrict__ len,
                          f16* __restrict__ x16h, f16* __restrict__ x16l,
                          f16* __restrict__ Bpk,
                          unsigned* __restrict__ hbw, unsigned* __restrict__ flags,
                          int* __restrict__ maxT, float* __restrict__ outp)
{
    const unsigned total = X16_ELEMS + BPK_HALF + HBUF_WORDS + FLAG_WORDS + 2u;
    for (unsigned e = blockIdx.x * blockDim.x + threadIdx.x; e < total;
         e += gridDim.x * blockDim.x) {
        if (e < X16_ELEMS) {
            unsigned k = e % 320u, r = e / 320u;   // r = b*512 + t
            float v = (k < 300u) ? x[r * 300u + k] : 0.0f;
            f16 hi = (f16)v;
            x16h[e] = hi;
            x16l[e] = (f16)((v - (float)hi) * 2048.0f);
        } else if (e < X16_ELEMS + BPK_HALF) {
            unsigned i = e - X16_ELEMS;
            // layout: [dir][p][term][nt][kt][lane][8]; this thread fills term=0 and term=1
            unsigned j    = i & 7u,  r1 = i >> 3;
            unsigned lane = r1 & 63u, r2 = r1 >> 6;
            unsigned kt   = r2 % 30u, r3 = r2 / 30u;
            unsigned nt   = r3 & 1u,  r4 = r3 >> 1;
            unsigned p    = r4 % 75u, dw = r4 / 75u;
            unsigned k = kt * 32u + (lane >> 4) * 8u + j;     // B[k][n], k-octet per quad
            unsigned n = nt * 16u + (lane & 15u);             // n = gate*8 + jj
            unsigned c = (n >> 3) * 600u + p * 8u + (n & 7u); // source column in [0,2400)
            float v = 0.0f;
            if (k < 300u)                    v = (dw ? Wb : Wf)[k * 2400u + c];
            else if (k >= 320u && k < 920u)  v = (dw ? Ub : Uf)[(k - 320u) * 2400u + c];
            f16 hi = (f16)v;
            unsigned base = (((((dw * 75u + p) * 2u + 0u) * 2u + nt) * 30u + kt) * 64u + lane) * 8u + j;
            Bpk[base]          = hi;
            Bpk[base + 30720u] = (f16)((v - (float)hi) * 2048.0f); // lo pre-scaled by 2^11
        } else if (e < X16_ELEMS + BPK_HALF + HBUF_WORDS) {
            hbw[e - X16_ELEMS - BPK_HALF] = 0u;   // zero all h ping-pong planes, both dirs
        } else if (e < X16_ELEMS + BPK_HALF + HBUF_WORDS + FLAG_WORDS) {
            unsigned q = e - (X16_ELEMS + BPK_HALF + HBUF_WORDS);
            // per-WG epoch flags; pad slots read as "always satisfied"
            flags[q] = ((q & 127u) < 75u) ? 0u : 0xFFFFFFFFu;
        } else {
            unsigned q = e - (X16_ELEMS + BPK_HALF + HBUF_WORDS + FLAG_WORDS);
            if (q == 0u) {
                int m = 1;
                for (int b = 0; b < 64; ++b) { int L = len[b]; m = (L > m) ? L : m; }
                *maxT = m;
            } else {
                // diagnostic sentinel: lstm_main always overwrites out[0]
                outp[0] = 1000.0f;
            }
        }
    }
}

// ---------------- main persistent recurrent kernel ----------------
__global__ __launch_bounds__(256, 1)
void lstm_main(const f16* __restrict__ x16h, const f16* __restrict__ x16l,
               const f16* __restrict__ Bpk,
               f16* __restrict__ hbuf, unsigned* flags, const int* __restrict__ maxT,
               const int* __restrict__ len,
               const float* __restrict__ bfv, const float* __restrict__ bbv,
               float* __restrict__ out)
{
    __shared__ f32x4 obox[4][4][2][64];   // [src_wave][mt][nt][lane] : 32 KB merge buffer
    __shared__ f16 hstage[2][64][8];      // h(hi,lo) transpose staging: 2 KB

    const int tid  = threadIdx.x;
    const int wave = tid >> 6, lane = tid & 63;
    const int quad = lane >> 4, l15 = lane & 15;
    const int dir  = blockIdx.x & 1, p = blockIdx.x >> 1;
    const int pc   = p * 8;

    // ---- persistent B fragments in VGPRs: this wave owns kt = wave + 4*s ----
    half8 Bf[8][2][2];
#pragma unroll
    for (int s = 0; s < 8; ++s) {
        int kt = wave + s * 4;
        if (kt < NKT) {
#pragma unroll
            for (int nt = 0; nt < 2; ++nt)
#pragma unroll
                for (int tm = 0; tm < 2; ++tm)
                    Bf[s][nt][tm] = *(const half8*)(Bpk +
                        (((((dir * 75 + p) * 2 + tm) * 2 + nt) * 30 + kt) * 64 + lane) * 8);
        }
    }
    const float* bias = dir ? bbv : bfv;
    const float bz0 = bias[((l15 >> 3)    ) * 600 + pc + (l15 & 7)];  // gates i|f tile
    const float bz1 = bias[((l15 >> 3) + 2) * 600 + pc + (l15 & 7)];  // gates g|o tile

    int Lm[4], Lr[4];
#pragma unroll
    for (int mt = 0; mt < 4; ++mt) Lm[mt] = len[mt * 16 + l15];        // A-load rows
#pragma unroll
    for (int r = 0; r < 4; ++r)   Lr[r]  = len[wave * 16 + quad * 4 + r]; // epilogue rows

    f16* hb0 = hbuf + dir * (2 * 2 * 64 * 640);     // [buf][plane][row][col]
    unsigned* myflags = flags + dir * 128;
    float cst[4] = {0, 0, 0, 0}, sum[4] = {0, 0, 0, 0};
    const int T = *maxT;

    for (int t = 0; t < T; ++t) {
        const f16* hcur = hb0 + (t & 1) * (2 * 64 * 640);
        f16*       hnxt = hb0 + ((t + 1) & 1) * (2 * 64 * 640);

        f32x4 accH[4][2], accM[4][2];
#pragma unroll
        for (int mt = 0; mt < 4; ++mt)
#pragma unroll
            for (int nt = 0; nt < 2; ++nt) {
                accH[mt][nt] = f32x4{0.f, 0.f, 0.f, 0.f};
                accM[mt][nt] = f32x4{0.f, 0.f, 0.f, 0.f};
            }

        // ---- x-part (kt<10): no dependence on h, overlaps flag wait ----
#pragma unroll
        for (int s = 0; s < 8; ++s) {
            int kt = wave + s * 4;
            if (kt < 10) {
#pragma unroll
                for (int mt = 0; mt < 4; ++mt) {
                    int row = mt * 16 + l15;
                    int tix = t;
                    if (dir) tix = (t < Lm[mt]) ? (Lm[mt] - 1 - t) : t;   // reverse_sequence
                    unsigned base = ((unsigned)row * 512u + (unsigned)tix) * 320u + kt * 32 + quad * 8;
                    half8 Ah = *(const half8*)(x16h + base);
                    half8 Al = *(const half8*)(x16l + base);
#pragma unroll
                    for (int nt = 0; nt < 2; ++nt) {
                        accH[mt][nt] = __builtin_amdgcn_mfma_f32_16x16x32_f16(Ah, Bf[s][nt][0], accH[mt][nt], 0, 0, 0);
                        accM[mt][nt] = __builtin_amdgcn_mfma_f32_16x16x32_f16(Ah, Bf[s][nt][1], accM[mt][nt], 0, 0, 0);
                        accM[mt][nt] = __builtin_amdgcn_mfma_f32_16x16x32_f16(Al, Bf[s][nt][0], accM[mt][nt], 0, 0, 0);
                    }
                }
            }
        }

        // ---- wait for h_t from all 75 producers of this direction ----
        if (t > 0) {
            const unsigned tgt = (unsigned)t;
            const unsigned long long* f8 = (const unsigned long long*)myflags;
            for (;;) {
                unsigned long long v = ~0ull;
                if (lane < 38)
                    v = __hip_atomic_load(&f8[lane], __ATOMIC_RELAXED, __HIP_MEMORY_SCOPE_AGENT);
                bool bad = ((unsigned)v < tgt) || ((unsigned)(v >> 32) < tgt);
                if (!__any(bad)) break;
                __builtin_amdgcn_s_sleep(1);
            }
            __builtin_amdgcn_fence(__ATOMIC_ACQUIRE, "agent");  // inv L1/L2 -> fresh h via cached loads
        }

        // ---- h-part (10<=kt<30) ----
#pragma unroll
        for (int s = 0; s < 8; ++s) {
            int kt = wave + s * 4;
            if (kt >= 10 && kt < NKT) {
#pragma unroll
                for (int mt = 0; mt < 4; ++mt) {
                    int row = mt * 16 + l15;
                    unsigned base = (unsigned)row * 640u + (kt * 32 - 320) + quad * 8;
                    half8 Ah = *(const half8*)(hcur + base);
                    half8 Al = *(const half8*)(hcur + 64 * 640 + base);
#pragma unroll
                    for (int nt = 0; nt < 2; ++nt) {
                        accH[mt][nt] = __builtin_amdgcn_mfma_f32_16x16x32_f16(Ah, Bf[s][nt][0], accH[mt][nt], 0, 0, 0);
                        accM[mt][nt] = __builtin_amdgcn_mfma_f32_16x16x32_f16(Ah, Bf[s][nt][1], accM[mt][nt], 0, 0, 0);
                        accM[mt][nt] = __builtin_amdgcn_mfma_f32_16x16x32_f16(Al, Bf[s][nt][0], accM[mt][nt], 0, 0, 0);
                    }
                }
            }
        }

        // ---- all-to-all K-merge through LDS ----
        __syncthreads();
#pragma unroll
        for (int mt = 0; mt < 4; ++mt)
#pragma unroll
            for (int nt = 0; nt < 2; ++nt)
                obox[wave][mt][nt][lane] = accH[mt][nt] + accM[mt][nt] * (1.0f / 2048.0f);
        __syncthreads();
        f32x4 z0 = obox[0][wave][0][lane] + obox[1][wave][0][lane]
                 + obox[2][wave][0][lane] + obox[3][wave][0][lane];
        f32x4 z1 = obox[0][wave][1][lane] + obox[1][wave][1][lane]
                 + obox[2][wave][1][lane] + obox[3][wave][1][lane];
        z0 += bz0;
        z1 += bz1;

        // ---- epilogue: this wave owns batch rows wave*16 .. wave*16+15 ----
#pragma unroll
        for (int r = 0; r < 4; ++r) {
            float zi = z0[r], zg = z1[r];
            float zf = __shfl_xor(z0[r], 8, 64);  // f gate lives 8 lanes over
            float zo = __shfl_xor(z1[r], 8, 64);
            if (l15 < 8) {
                float ig = 1.0f / (1.0f + __expf(-zi));
                float fg = 1.0f / (1.0f + __expf(-zf));
                float gg = tanhf(zg);
                float og = 1.0f / (1.0f + __expf(-zo));
                float c  = fg * cst[r] + ig * gg;
                cst[r] = c;
                float h = og * tanhf(c);
                if (t < Lr[r]) sum[r] += h;
                f16 hh = (f16)h;
                f16 hl = (f16)((h - (float)hh) * 2048.0f);
                int row = wave * 16 + quad * 4 + r;
                hstage[0][row][l15] = hh;
                hstage[1][row][l15] = hl;
            }
        }
        __syncthreads();   // hstage complete
        {
            // 256 threads publish 256 x 8B write-through stores (rows x planes)
            int pl = tid >> 7, rr = (tid >> 1) & 63, hf = tid & 1;
            unsigned long long v = *(const unsigned long long*)&hstage[pl][rr][hf * 4];
            __hip_atomic_store(
                (unsigned long long*)(hnxt + pl * (64 * 640) + (unsigned)rr * 640u + pc + hf * 4),
                v, __ATOMIC_RELAXED, __HIP_MEMORY_SCOPE_AGENT);
        }
        __syncthreads();   // drains all waves' stores (vmcnt(0) before barrier)
        if (tid == 0)
            __hip_atomic_store(myflags + p, (unsigned)(t + 1),
                               __ATOMIC_RELEASE, __HIP_MEMORY_SCOPE_AGENT);
    }

    if (l15 < 8) {
#pragma unroll
        for (int r = 0; r < 4; ++r)
            out[(wave * 16 + quad * 4 + r) * 1200 + dir * 600 + pc + l15] =
                sum[r] * (1.0f / 512.0f);
    }
}

// ---------------- launcher ----------------
extern "C" void kernel_launch(void* const* d_in, const int* in_sizes, int n_in,
                              void* d_out, int out_size, void* d_ws, size_t ws_size,
                              hipStream_t stream) {
    const float* x   = (const float*)d_in[0];
    const int*   len = (const int*)  d_in[1];
    const float* Wf  = (const float*)d_in[3];
    const float* Uf  = (const float*)d_in[4];
    const float* bfv = (const float*)d_in[5];
    const float* Wb  = (const float*)d_in[6];
    const float* Ub  = (const float*)d_in[7];
    const float* bbv = (const float*)d_in[8];
    float* outp = (float*)d_out;

    char* w = (char*)d_ws;
    f16*      x16hp = (f16*)w;                         // 20,971,520 B
    f16*      x16lp = (f16*)(w + 20971520);            // 20,971,520 B
    f16*      bpkp  = (f16*)(w + 41943040);            // 18,432,000 B
    f16*      hbufp = (f16*)(w + 60375040);            //  1,310,720 B (planes)
    unsigned* flagp = (unsigned*)(w + 61741056);       //      1,024 B
    int*      maxtp = (int*)(w + 61742080);

    hipLaunchKernelGGL(lstm_prep, dim3(1024), dim3(256), 0, stream,
                       x, Wf, Uf, Wb, Ub, len,
                       x16hp, x16lp, bpkp, (unsigned*)hbufp, flagp, maxtp, outp);

    hipLaunchKernelGGL(lstm_main, dim3(GRID_MAIN), dim3(256), 0, stream,
                       x16hp, x16lp, bpkp, hbufp, flagp, maxtp, len, bfv, bbv, outp);
}

// Round 5
// 9941.946 us; speedup vs baseline: 1.0729x; 1.0729x over previous
//
#include <hip/hip_runtime.h>
#include <hip/hip_fp16.h>
#include <cmath>

typedef _Float16 f16;
typedef _Float16 half8 __attribute__((ext_vector_type(8)));
typedef float f32x4 __attribute__((ext_vector_type(4)));

#define P_WG   75          // workgroups per direction
#define NKT    30          // K tiles of 32: 10 x-part + 20 h-part
#define GRID_MAIN (2*P_WG) // 150
#define G      12          // steps per XZ burst

#define X16_ELEMS  (64u*512u*320u)            // 10,485,760 f16 per plane
#define BPK_HALF   (2u*75u*2u*30u*64u*8u)     // 4,608,000 f16 (one term plane)
#define HBUF_F16   (2u*2u*64u*640u)           // dirs*bufs*rows*cols = 163,840 f16 (single plane)
#define HBUF_WORDS (HBUF_F16/2u)              // 81,920 u32
#define FLAG_WORDS 256u                       // 2 dirs x 128 u32 (75 used + pad)

// ---------------- prep: rebuild all workspace state every launch ----------------
__global__ void lstm_prep(const float* __restrict__ x,
                          const float* __restrict__ Wf, const float* __restrict__ Uf,
                          const float* __restrict__ Wb, const float* __restrict__ Ub,
                          const int* __restrict__ len,
                          f16* __restrict__ x16h, f16* __restrict__ x16l,
                          f16* __restrict__ Bpk,
                          unsigned* __restrict__ hbw, unsigned* __restrict__ flags,
                          int* __restrict__ maxT, float* __restrict__ outp)
{
    const unsigned total = X16_ELEMS + BPK_HALF + HBUF_WORDS + FLAG_WORDS + 2u;
    for (unsigned e = blockIdx.x * blockDim.x + threadIdx.x; e < total;
         e += gridDim.x * blockDim.x) {
        if (e < X16_ELEMS) {
            unsigned k = e % 320u, r = e / 320u;   // r = b*512 + t
            float v = (k < 300u) ? x[r * 300u + k] : 0.0f;
            f16 hi = (f16)v;
            x16h[e] = hi;
            x16l[e] = (f16)((v - (float)hi) * 2048.0f);
        } else if (e < X16_ELEMS + BPK_HALF) {
            unsigned i = e - X16_ELEMS;
            // layout: [dir][p][term][nt][kt][lane][8]
            unsigned j    = i & 7u,  r1 = i >> 3;
            unsigned lane = r1 & 63u, r2 = r1 >> 6;
            unsigned kt   = r2 % 30u, r3 = r2 / 30u;
            unsigned nt   = r3 & 1u,  r4 = r3 >> 1;
            unsigned p    = r4 % 75u, dw = r4 / 75u;
            unsigned k = kt * 32u + (lane >> 4) * 8u + j;     // B[k][n], k-octet per quad
            unsigned n = nt * 16u + (lane & 15u);             // n = gate*8 + jj
            unsigned c = (n >> 3) * 600u + p * 8u + (n & 7u); // source column in [0,2400)
            float v = 0.0f;
            if (k < 300u)                    v = (dw ? Wb : Wf)[k * 2400u + c];
            else if (k >= 320u && k < 920u)  v = (dw ? Ub : Uf)[(k - 320u) * 2400u + c];
            f16 hi = (f16)v;
            unsigned base = (((((dw * 75u + p) * 2u + 0u) * 2u + nt) * 30u + kt) * 64u + lane) * 8u + j;
            Bpk[base]          = hi;
            Bpk[base + 30720u] = (f16)((v - (float)hi) * 2048.0f); // lo pre-scaled by 2^11
        } else if (e < X16_ELEMS + BPK_HALF + HBUF_WORDS) {
            hbw[e - X16_ELEMS - BPK_HALF] = 0u;   // zero h ping-pong buffers, both dirs
        } else if (e < X16_ELEMS + BPK_HALF + HBUF_WORDS + FLAG_WORDS) {
            unsigned q = e - (X16_ELEMS + BPK_HALF + HBUF_WORDS);
            flags[q] = ((q & 127u) < 75u) ? 0u : 0xFFFFFFFFu;  // pads always satisfied
        } else {
            unsigned q = e - (X16_ELEMS + BPK_HALF + HBUF_WORDS + FLAG_WORDS);
            if (q == 0u) {
                int m = 1;
                for (int b = 0; b < 64; ++b) { int L = len[b]; m = (L > m) ? L : m; }
                *maxT = m;
            } else {
                outp[0] = 1000.0f;   // sentinel: lstm_main always overwrites out[0]
            }
        }
    }
}

// ---------------- main persistent recurrent kernel ----------------
__global__ __launch_bounds__(256, 1)
void lstm_main(const f16* __restrict__ x16h, const f16* __restrict__ x16l,
               const f16* __restrict__ Bpk,
               f16* __restrict__ hbuf, float* __restrict__ xz,
               unsigned* flags, const int* __restrict__ maxT,
               const int* __restrict__ len,
               const float* __restrict__ bfv, const float* __restrict__ bbv,
               float* __restrict__ out)
{
    __shared__ f32x4 obox[4][4][2][64];   // [src_wave][mt][nt][lane] : 32 KB merge buffer
    __shared__ f16 hstage[64][8];         // h transpose staging: 1 KB

    const int tid  = threadIdx.x;
    const int wave = tid >> 6, lane = tid & 63;
    const int quad = lane >> 4, l15 = lane & 15;
    const int dir  = blockIdx.x & 1, p = blockIdx.x >> 1;
    const int pc   = p * 8;
    const int wg   = blockIdx.x;

    // ---- resident h-part B fragments: this wave owns 5 kt values >= 10 ----
    const int s0 = (wave < 2) ? 3 : 2;    // kt = wave + 4*(s0+sp), sp=0..4
    half8 Bh[5][2][2];
#pragma unroll
    for (int sp = 0; sp < 5; ++sp) {
        int kt = wave + 4 * (s0 + sp);
#pragma unroll
        for (int nt = 0; nt < 2; ++nt)
#pragma unroll
            for (int tm = 0; tm < 2; ++tm)
                Bh[sp][nt][tm] = *(const half8*)(Bpk +
                    (((((dir * 75 + p) * 2 + tm) * 2 + nt) * 30 + kt) * 64 + lane) * 8);
    }
    const float* bias = dir ? bbv : bfv;
    const float b0 = bias[((l15 >> 3)    ) * 600 + pc + (l15 & 7)];  // gates i|f tile
    const float b1 = bias[((l15 >> 3) + 2) * 600 + pc + (l15 & 7)];  // gates g|o tile

    int Lm[4], Lr[4];
#pragma unroll
    for (int mt = 0; mt < 4; ++mt) Lm[mt] = len[mt * 16 + l15];        // burst A rows
#pragma unroll
    for (int r = 0; r < 4; ++r)   Lr[r]  = len[wave * 16 + quad * 4 + r]; // epilogue rows

    f16* hb0 = hbuf + dir * (2 * 64 * 640);
    unsigned* myflags = flags + dir * 128;
    float* myxz = xz + (size_t)wg * (G * 64 * 32);
    float cst[4] = {0, 0, 0, 0}, sum[4] = {0, 0, 0, 0};
    const int T = *maxT;

    for (int t = 0; t < T; ++t) {
        // ---- burst: precompute XZ = x*W + b for steps t..t+G-1 (WG-local) ----
        if ((t % G) == 0) {
#pragma unroll
            for (int jc = 0; jc < 3; ++jc) {
                int g  = wave * 3 + jc;
                int tb = t + g; int tt = (tb < 512) ? tb : 511;
                unsigned arow[4];
#pragma unroll
                for (int mt = 0; mt < 4; ++mt) {
                    int tx = tt;
                    if (dir) tx = (tt < Lm[mt]) ? (Lm[mt] - 1 - tt) : tt;  // reverse_sequence
                    arow[mt] = ((unsigned)(mt * 16 + l15) * 512u + (unsigned)tx) * 320u + quad * 8;
                }
                f32x4 aH[4][2], aM[4][2];
#pragma unroll
                for (int mt = 0; mt < 4; ++mt)
#pragma unroll
                    for (int nt = 0; nt < 2; ++nt) {
                        aH[mt][nt] = f32x4{0.f, 0.f, 0.f, 0.f};
                        aM[mt][nt] = f32x4{0.f, 0.f, 0.f, 0.f};
                    }
#pragma unroll
                for (int kt = 0; kt < 10; ++kt) {
                    const f16* bb = Bpk + ((unsigned)(dir * 75 + p) * 4u * 30u + kt) * 64u * 8u + lane * 8;
                    half8 B00 = *(const half8*)(bb);                      // tm=0,nt=0
                    half8 B01 = *(const half8*)(bb + 30u * 64u * 8u);     // tm=0,nt=1
                    half8 B10 = *(const half8*)(bb + 60u * 64u * 8u);     // tm=1,nt=0
                    half8 B11 = *(const half8*)(bb + 90u * 64u * 8u);     // tm=1,nt=1
#pragma unroll
                    for (int mt = 0; mt < 4; ++mt) {
                        half8 Ah = *(const half8*)(x16h + arow[mt] + kt * 32);
                        half8 Al = *(const half8*)(x16l + arow[mt] + kt * 32);
                        aH[mt][0] = __builtin_amdgcn_mfma_f32_16x16x32_f16(Ah, B00, aH[mt][0], 0, 0, 0);
                        aM[mt][0] = __builtin_amdgcn_mfma_f32_16x16x32_f16(Ah, B10, aM[mt][0], 0, 0, 0);
                        aM[mt][0] = __builtin_amdgcn_mfma_f32_16x16x32_f16(Al, B00, aM[mt][0], 0, 0, 0);
                        aH[mt][1] = __builtin_amdgcn_mfma_f32_16x16x32_f16(Ah, B01, aH[mt][1], 0, 0, 0);
                        aM[mt][1] = __builtin_amdgcn_mfma_f32_16x16x32_f16(Ah, B11, aM[mt][1], 0, 0, 0);
                        aM[mt][1] = __builtin_amdgcn_mfma_f32_16x16x32_f16(Al, B01, aM[mt][1], 0, 0, 0);
                    }
                }
                // write-through (never dirty in L2 -> survives buffer_inv)
#pragma unroll
                for (int mt = 0; mt < 4; ++mt)
#pragma unroll
                    for (int r = 0; r < 4; ++r) {
                        unsigned rowi = (unsigned)(g * 64 + mt * 16 + quad * 4 + r) * 32u;
                        __hip_atomic_store(&myxz[rowi + l15],
                                           aH[mt][0][r] + aM[mt][0][r] * (1.0f / 2048.0f) + b0,
                                           __ATOMIC_RELAXED, __HIP_MEMORY_SCOPE_AGENT);
                        __hip_atomic_store(&myxz[rowi + 16 + l15],
                                           aH[mt][1][r] + aM[mt][1][r] * (1.0f / 2048.0f) + b1,
                                           __ATOMIC_RELAXED, __HIP_MEMORY_SCOPE_AGENT);
                    }
            }
            __syncthreads();   // XZ visible to all waves before consumption
        }

        // ---- pre-load this step's XZ into registers (before wait; fence-immune) ----
        float z0p[4], z1p[4];
        {
            int g = t % G;
            unsigned rbase = (unsigned)(g * 64 + wave * 16 + quad * 4) * 32u;
#pragma unroll
            for (int r = 0; r < 4; ++r) {
                z0p[r] = myxz[rbase + r * 32 + l15];
                z1p[r] = myxz[rbase + r * 32 + 16 + l15];
            }
        }

        const f16* hcur = hb0 + (t & 1) * (64 * 640);
        f16*       hnxt = hb0 + ((t + 1) & 1) * (64 * 640);

        // ---- wait for h_t from all 75 producers of this direction ----
        if (t > 0) {
            const unsigned tgt = (unsigned)t;
            const unsigned long long* f8 = (const unsigned long long*)myflags;
            for (;;) {
                unsigned long long v = ~0ull;
                if (lane < 38)
                    v = __hip_atomic_load(&f8[lane], __ATOMIC_RELAXED, __HIP_MEMORY_SCOPE_AGENT);
                bool bad = ((unsigned)v < tgt) || ((unsigned)(v >> 32) < tgt);
                if (!__any(bad)) break;
                __builtin_amdgcn_s_sleep(3);
            }
            __builtin_amdgcn_fence(__ATOMIC_ACQUIRE, "agent");  // inv L1/L2 -> fresh h
        }

        // ---- h-part MFMAs (single-plane h) ----
        f32x4 accH[4][2], accM[4][2];
#pragma unroll
        for (int mt = 0; mt < 4; ++mt)
#pragma unroll
            for (int nt = 0; nt < 2; ++nt) {
                accH[mt][nt] = f32x4{0.f, 0.f, 0.f, 0.f};
                accM[mt][nt] = f32x4{0.f, 0.f, 0.f, 0.f};
            }
#pragma unroll
        for (int sp = 0; sp < 5; ++sp) {
            int kt = wave + 4 * (s0 + sp);
#pragma unroll
            for (int mt = 0; mt < 4; ++mt) {
                int row = mt * 16 + l15;
                half8 Ah = *(const half8*)(hcur + (unsigned)row * 640u + (kt * 32 - 320) + quad * 8);
#pragma unroll
                for (int nt = 0; nt < 2; ++nt) {
                    accH[mt][nt] = __builtin_amdgcn_mfma_f32_16x16x32_f16(Ah, Bh[sp][nt][0], accH[mt][nt], 0, 0, 0);
                    accM[mt][nt] = __builtin_amdgcn_mfma_f32_16x16x32_f16(Ah, Bh[sp][nt][1], accM[mt][nt], 0, 0, 0);
                }
            }
        }

        // ---- all-to-all K-merge through LDS ----
        __syncthreads();
#pragma unroll
        for (int mt = 0; mt < 4; ++mt)
#pragma unroll
            for (int nt = 0; nt < 2; ++nt)
                obox[wave][mt][nt][lane] = accH[mt][nt] + accM[mt][nt] * (1.0f / 2048.0f);
        __syncthreads();
        f32x4 z0 = obox[0][wave][0][lane] + obox[1][wave][0][lane]
                 + obox[2][wave][0][lane] + obox[3][wave][0][lane];
        f32x4 z1 = obox[0][wave][1][lane] + obox[1][wave][1][lane]
                 + obox[2][wave][1][lane] + obox[3][wave][1][lane];
        z0 += f32x4{z0p[0], z0p[1], z0p[2], z0p[3]};
        z1 += f32x4{z1p[0], z1p[1], z1p[2], z1p[3]};

        // ---- epilogue: this wave owns batch rows wave*16 .. wave*16+15 ----
#pragma unroll
        for (int r = 0; r < 4; ++r) {
            float zi = z0[r], zg = z1[r];
            float zf = __shfl_xor(z0[r], 8, 64);  // f gate lives 8 lanes over
            float zo = __shfl_xor(z1[r], 8, 64);
            if (l15 < 8) {
                float ig = 1.0f / (1.0f + __expf(-zi));
                float fg = 1.0f / (1.0f + __expf(-zf));
                float gg = tanhf(zg);
                float og = 1.0f / (1.0f + __expf(-zo));
                float c  = fg * cst[r] + ig * gg;
                cst[r] = c;
                float h = og * tanhf(c);
                if (t < Lr[r]) sum[r] += h;
                hstage[wave * 16 + quad * 4 + r][l15] = (f16)h;
            }
        }
        __syncthreads();   // hstage complete
        if (tid < 128) {
            // 128 threads publish 128 x 8B write-through stores
            int rr = tid >> 1, hf = tid & 1;
            unsigned long long v = *(const unsigned long long*)&hstage[rr][hf * 4];
            __hip_atomic_store(
                (unsigned long long*)(hnxt + (unsigned)rr * 640u + pc + hf * 4),
                v, __ATOMIC_RELAXED, __HIP_MEMORY_SCOPE_AGENT);
        }
        __syncthreads();   // drains all waves' stores before the flag release
        if (tid == 0)
            __hip_atomic_store(myflags + p, (unsigned)(t + 1),
                               __ATOMIC_RELEASE, __HIP_MEMORY_SCOPE_AGENT);
    }

    if (l15 < 8) {
#pragma unroll
        for (int r = 0; r < 4; ++r)
            out[(wave * 16 + quad * 4 + r) * 1200 + dir * 600 + pc + l15] =
                sum[r] * (1.0f / 512.0f);
    }
}

// ---------------- launcher ----------------
extern "C" void kernel_launch(void* const* d_in, const int* in_sizes, int n_in,
                              void* d_out, int out_size, void* d_ws, size_t ws_size,
                              hipStream_t stream) {
    const float* x   = (const float*)d_in[0];
    const int*   len = (const int*)  d_in[1];
    const float* Wf  = (const float*)d_in[3];
    const float* Uf  = (const float*)d_in[4];
    const float* bfv = (const float*)d_in[5];
    const float* Wb  = (const float*)d_in[6];
    const float* Ub  = (const float*)d_in[7];
    const float* bbv = (const float*)d_in[8];
    float* outp = (float*)d_out;

    char* w = (char*)d_ws;
    f16*      x16hp = (f16*)w;                         // 20,971,520 B
    f16*      x16lp = (f16*)(w + 20971520);            // 20,971,520 B
    f16*      bpkp  = (f16*)(w + 41943040);            // 18,432,000 B
    f16*      hbufp = (f16*)(w + 60375040);            //    327,680 B
    float*    xzp   = (float*)(w + 60702720);          // 14,745,600 B
    unsigned* flagp = (unsigned*)(w + 75448320);       //      1,024 B
    int*      maxtp = (int*)(w + 75449344);

    hipLaunchKernelGGL(lstm_prep, dim3(1024), dim3(256), 0, stream,
                       x, Wf, Uf, Wb, Ub, len,
                       x16hp, x16lp, bpkp, (unsigned*)hbufp, flagp, maxtp, outp);

    hipLaunchKernelGGL(lstm_main, dim3(GRID_MAIN), dim3(256), 0, stream,
                       x16hp, x16lp, bpkp, hbufp, xzp, flagp, maxtp, len, bfv, bbv, outp);
}

// Round 6
// 5692.186 us; speedup vs baseline: 1.8738x; 1.7466x over previous
//
#include <hip/hip_runtime.h>
#include <hip/hip_fp16.h>
#include <cmath>

typedef _Float16 f16;
typedef _Float16 half8 __attribute__((ext_vector_type(8)));
typedef float f32x4 __attribute__((ext_vector_type(4)));

#define P_WG   75          // workgroups per direction
#define GRID_MAIN (2*P_WG) // 150
#define G      12          // XZ lookahead distance
#define RING   13          // XZ ring slots (G+1)

#define X16_ELEMS  (64u*512u*320u)            // 10,485,760 f16 per plane
#define BPK_HALF   (2u*75u*2u*30u*64u*8u)     // 4,608,000 f16 (one term plane)
#define HBUF_F16   (2u*2u*64u*640u)           // dirs*bufs*rows*cols f16
#define HBUF_WORDS (HBUF_F16/2u)              // 81,920 u32
#define FLAG_WORDS 256u                       // 2 dirs x 128 u32 (75 flags + E word)
#define E_OFF      96u                        // epoch word offset inside a dir block

// ---------------- prep: rebuild all workspace state every launch ----------------
__global__ void lstm_prep(const float* __restrict__ x,
                          const float* __restrict__ Wf, const float* __restrict__ Uf,
                          const float* __restrict__ Wb, const float* __restrict__ Ub,
                          const int* __restrict__ len,
                          f16* __restrict__ x16h, f16* __restrict__ x16l,
                          f16* __restrict__ Bpk,
                          unsigned* __restrict__ hbw, unsigned* __restrict__ flags,
                          int* __restrict__ maxT, float* __restrict__ outp)
{
    const unsigned total = X16_ELEMS + BPK_HALF + HBUF_WORDS + FLAG_WORDS + 2u;
    for (unsigned e = blockIdx.x * blockDim.x + threadIdx.x; e < total;
         e += gridDim.x * blockDim.x) {
        if (e < X16_ELEMS) {
            unsigned k = e % 320u, r = e / 320u;   // r = b*512 + t
            float v = (k < 300u) ? x[r * 300u + k] : 0.0f;
            f16 hi = (f16)v;
            x16h[e] = hi;
            x16l[e] = (f16)((v - (float)hi) * 2048.0f);
        } else if (e < X16_ELEMS + BPK_HALF) {
            unsigned i = e - X16_ELEMS;
            // layout: [dir][p][term][nt][kt][lane][8]
            unsigned j    = i & 7u,  r1 = i >> 3;
            unsigned lane = r1 & 63u, r2 = r1 >> 6;
            unsigned kt   = r2 % 30u, r3 = r2 / 30u;
            unsigned nt   = r3 & 1u,  r4 = r3 >> 1;
            unsigned p    = r4 % 75u, dw = r4 / 75u;
            unsigned k = kt * 32u + (lane >> 4) * 8u + j;     // B[k][n], k-octet per quad
            unsigned n = nt * 16u + (lane & 15u);             // n = gate*8 + jj
            unsigned c = (n >> 3) * 600u + p * 8u + (n & 7u); // source column in [0,2400)
            float v = 0.0f;
            if (k < 300u)                    v = (dw ? Wb : Wf)[k * 2400u + c];
            else if (k >= 320u && k < 920u)  v = (dw ? Ub : Uf)[(k - 320u) * 2400u + c];
            f16 hi = (f16)v;
            unsigned base = (((((dw * 75u + p) * 2u + 0u) * 2u + nt) * 30u + kt) * 64u + lane) * 8u + j;
            Bpk[base]          = hi;
            Bpk[base + 30720u] = (f16)((v - (float)hi) * 2048.0f); // lo pre-scaled by 2^11
        } else if (e < X16_ELEMS + BPK_HALF + HBUF_WORDS) {
            hbw[e - X16_ELEMS - BPK_HALF] = 0u;   // zero h ping-pong buffers, both dirs
        } else if (e < X16_ELEMS + BPK_HALF + HBUF_WORDS + FLAG_WORDS) {
            unsigned q = e - (X16_ELEMS + BPK_HALF + HBUF_WORDS);
            unsigned q7 = q & 127u;
            flags[q] = (q7 < 75u || q7 == E_OFF) ? 0u : 0xFFFFFFFFu; // pads always satisfied
        } else {
            unsigned q = e - (X16_ELEMS + BPK_HALF + HBUF_WORDS + FLAG_WORDS);
            if (q == 0u) {
                int m = 1;
                for (int b = 0; b < 64; ++b) { int L = len[b]; m = (L > m) ? L : m; }
                *maxT = m;
            } else {
                outp[0] = 1000.0f;   // sentinel: lstm_main always overwrites out[0]
            }
        }
    }
}

// MALL-direct 16B load as 2x8B agent-scope atomic loads (bypass L1/L2 -> always fresh)
__device__ __forceinline__ half8 ld_h8_mall(const f16* p) {
    union { unsigned long long u[2]; half8 h; } x;
    x.u[0] = __hip_atomic_load((const unsigned long long*)p,     __ATOMIC_RELAXED, __HIP_MEMORY_SCOPE_AGENT);
    x.u[1] = __hip_atomic_load((const unsigned long long*)p + 1, __ATOMIC_RELAXED, __HIP_MEMORY_SCOPE_AGENT);
    return x.h;
}

// ---------------- main persistent recurrent kernel ----------------
__global__ __launch_bounds__(256, 1)
void lstm_main(const f16* __restrict__ x16h, const f16* __restrict__ x16l,
               const f16* __restrict__ Bpk,
               f16* __restrict__ hbuf, float* __restrict__ xz,
               unsigned* flags, const int* __restrict__ maxT,
               const int* __restrict__ len,
               const float* __restrict__ bfv, const float* __restrict__ bbv,
               float* __restrict__ out)
{
    __shared__ f32x4 obox[4][4][2][64];   // [src_wave][mt][nt][lane] : 32 KB merge buffer
    __shared__ f16 hstage[64][8];         // h transpose staging: 1 KB
    __shared__ char ldspad[52000];        // force 1 WG/CU

    const int tid  = threadIdx.x;
    const int wave = tid >> 6, lane = tid & 63;
    const int quad = lane >> 4, l15 = lane & 15;
    const int dir  = blockIdx.x & 1, p = blockIdx.x >> 1;
    const int pc   = p * 8;
    const int wg   = blockIdx.x;

    if (maxT == nullptr) ldspad[tid] = 1;  // never true; keeps pad allocated

    // ---- resident h-part B fragments: this wave owns 5 kt values in [10,30) ----
    const int s0 = (wave < 2) ? 3 : 2;    // kt = wave + 4*(s0+sp), sp=0..4
    half8 Bh[5][2][2];
#pragma unroll
    for (int sp = 0; sp < 5; ++sp) {
        int kt = wave + 4 * (s0 + sp);
#pragma unroll
        for (int nt = 0; nt < 2; ++nt)
#pragma unroll
            for (int tm = 0; tm < 2; ++tm)
                Bh[sp][nt][tm] = *(const half8*)(Bpk +
                    (((((dir * 75 + p) * 2 + tm) * 2 + nt) * 30 + kt) * 64 + lane) * 8);
    }
    const float* bias = dir ? bbv : bfv;
    const float b0 = bias[((l15 >> 3)    ) * 600 + pc + (l15 & 7)];  // gates i|f tile
    const float b1 = bias[((l15 >> 3) + 2) * 600 + pc + (l15 & 7)];  // gates g|o tile

    int Lm[4], Lr[4];
#pragma unroll
    for (int mt = 0; mt < 4; ++mt) Lm[mt] = len[mt * 16 + l15];        // initial-burst A rows
    const int Lw = len[wave * 16 + l15];                               // steady-burst A rows (mt=wave)
#pragma unroll
    for (int r = 0; r < 4; ++r)   Lr[r]  = len[wave * 16 + quad * 4 + r]; // epilogue rows

    f16* hb0 = hbuf + dir * (2 * 64 * 640);
    unsigned* myflags = flags + dir * 128;
    float* myxz = xz + (size_t)wg * (RING * 64 * 32);
    float cst[4] = {0, 0, 0, 0}, sum[4] = {0, 0, 0, 0};
    const int T = *maxT;
    const unsigned bpk_base = (unsigned)(dir * 75 + p) * 4u * 30u * 512u;  // [dir][p] block, elems

    // ---- initial burst: fill XZ ring slots 0..G-1 (wave g-split, full K) ----
#pragma unroll
    for (int jc = 0; jc < 3; ++jc) {
        int g = wave * 3 + jc;
        int tt = (g < 512) ? g : 511;
        unsigned arow[4];
#pragma unroll
        for (int mt = 0; mt < 4; ++mt) {
            int tx = tt;
            if (dir) tx = (tt < Lm[mt]) ? (Lm[mt] - 1 - tt) : tt;  // reverse_sequence
            arow[mt] = ((unsigned)(mt * 16 + l15) * 512u + (unsigned)tx) * 320u + quad * 8;
        }
        f32x4 aH[4][2], aM[4][2];
#pragma unroll
        for (int mt = 0; mt < 4; ++mt)
#pragma unroll
            for (int nt = 0; nt < 2; ++nt) {
                aH[mt][nt] = f32x4{0.f, 0.f, 0.f, 0.f};
                aM[mt][nt] = f32x4{0.f, 0.f, 0.f, 0.f};
            }
#pragma unroll
        for (int kt = 0; kt < 10; ++kt) {
            const f16* bb = Bpk + bpk_base + kt * 512u + lane * 8;
            half8 B00 = *(const half8*)(bb);
            half8 B01 = *(const half8*)(bb + 15360);
            half8 B10 = *(const half8*)(bb + 30720);
            half8 B11 = *(const half8*)(bb + 46080);
#pragma unroll
            for (int mt = 0; mt < 4; ++mt) {
                half8 Ah = *(const half8*)(x16h + arow[mt] + kt * 32);
                half8 Al = *(const half8*)(x16l + arow[mt] + kt * 32);
                aH[mt][0] = __builtin_amdgcn_mfma_f32_16x16x32_f16(Ah, B00, aH[mt][0], 0, 0, 0);
                aM[mt][0] = __builtin_amdgcn_mfma_f32_16x16x32_f16(Ah, B10, aM[mt][0], 0, 0, 0);
                aM[mt][0] = __builtin_amdgcn_mfma_f32_16x16x32_f16(Al, B00, aM[mt][0], 0, 0, 0);
                aH[mt][1] = __builtin_amdgcn_mfma_f32_16x16x32_f16(Ah, B01, aH[mt][1], 0, 0, 0);
                aM[mt][1] = __builtin_amdgcn_mfma_f32_16x16x32_f16(Ah, B11, aM[mt][1], 0, 0, 0);
                aM[mt][1] = __builtin_amdgcn_mfma_f32_16x16x32_f16(Al, B01, aM[mt][1], 0, 0, 0);
            }
        }
#pragma unroll
        for (int mt = 0; mt < 4; ++mt)
#pragma unroll
            for (int r = 0; r < 4; ++r) {
                unsigned rowi = (unsigned)(g * 64 + mt * 16 + quad * 4 + r) * 32u;
                myxz[rowi + l15]      = aH[mt][0][r] + aM[mt][0][r] * (1.0f / 2048.0f) + b0;
                myxz[rowi + 16 + l15] = aH[mt][1][r] + aM[mt][1][r] * (1.0f / 2048.0f) + b1;
            }
    }
    __syncthreads();   // XZ slots 0..11 visible WG-wide (same CU: L1-coherent)

    for (int t = 0; t < T; ++t) {
        // ---- pipelined burst: compute XZ for step t+G (this wave's 16 rows, full K) ----
        int tf = t + G;
        if (tf < T) {
            int tx = tf;
            if (dir) tx = (tf < Lw) ? (Lw - 1 - tf) : tf;
            unsigned arow = ((unsigned)(wave * 16 + l15) * 512u + (unsigned)tx) * 320u + quad * 8;
            f32x4 aH[2], aM[2];
            aH[0] = f32x4{0.f, 0.f, 0.f, 0.f}; aM[0] = f32x4{0.f, 0.f, 0.f, 0.f};
            aH[1] = f32x4{0.f, 0.f, 0.f, 0.f}; aM[1] = f32x4{0.f, 0.f, 0.f, 0.f};
#pragma unroll
            for (int kt = 0; kt < 10; ++kt) {
                const f16* bb = Bpk + bpk_base + kt * 512u + lane * 8;
                half8 B00 = *(const half8*)(bb);
                half8 B01 = *(const half8*)(bb + 15360);
                half8 B10 = *(const half8*)(bb + 30720);
                half8 B11 = *(const half8*)(bb + 46080);
                half8 Ah = *(const half8*)(x16h + arow + kt * 32);
                half8 Al = *(const half8*)(x16l + arow + kt * 32);
                aH[0] = __builtin_amdgcn_mfma_f32_16x16x32_f16(Ah, B00, aH[0], 0, 0, 0);
                aM[0] = __builtin_amdgcn_mfma_f32_16x16x32_f16(Ah, B10, aM[0], 0, 0, 0);
                aM[0] = __builtin_amdgcn_mfma_f32_16x16x32_f16(Al, B00, aM[0], 0, 0, 0);
                aH[1] = __builtin_amdgcn_mfma_f32_16x16x32_f16(Ah, B01, aH[1], 0, 0, 0);
                aM[1] = __builtin_amdgcn_mfma_f32_16x16x32_f16(Ah, B11, aM[1], 0, 0, 0);
                aM[1] = __builtin_amdgcn_mfma_f32_16x16x32_f16(Al, B01, aM[1], 0, 0, 0);
            }
            int slot = tf % RING;
#pragma unroll
            for (int r = 0; r < 4; ++r) {
                unsigned rowi = (unsigned)(slot * 64 + wave * 16 + quad * 4 + r) * 32u;
                myxz[rowi + l15]      = aH[0][r] + aM[0][r] * (1.0f / 2048.0f) + b0;
                myxz[rowi + 16 + l15] = aH[1][r] + aM[1][r] * (1.0f / 2048.0f) + b1;
            }
        }

        // ---- preload this step's XZ into registers (WG-local, L1-warm) ----
        float z0p[4], z1p[4];
        {
            int slot = t % RING;
            unsigned rbase = (unsigned)(slot * 64 + wave * 16 + quad * 4) * 32u;
#pragma unroll
            for (int r = 0; r < 4; ++r) {
                z0p[r] = myxz[rbase + r * 32 + l15];
                z1p[r] = myxz[rbase + r * 32 + 16 + l15];
            }
        }

        const f16* hcur = hb0 + (t & 1) * (64 * 640);
        f16*       hnxt = hb0 + ((t + 1) & 1) * (64 * 640);

        // ---- wait: aggregated epoch broadcast (NO acquire fence anywhere) ----
        if (t > 0) {
            const unsigned tgt = (unsigned)t;
            if (p == 0 && wave == 0) {
                // aggregator: sole reader of the 75 raw flags
                const unsigned long long* f8 = (const unsigned long long*)myflags;
                for (;;) {
                    unsigned long long v = ~0ull;
                    if (lane < 38)
                        v = __hip_atomic_load(&f8[lane], __ATOMIC_RELAXED, __HIP_MEMORY_SCOPE_AGENT);
                    bool bad = ((unsigned)v < tgt) || ((unsigned)(v >> 32) < tgt);
                    if (!__any(bad)) break;
                    __builtin_amdgcn_s_sleep(1);
                }
                if (lane == 0)
                    __hip_atomic_store(myflags + E_OFF, tgt,
                                       __ATOMIC_RELAXED, __HIP_MEMORY_SCOPE_AGENT);
            } else {
                // consumers: one coalesced same-address load per wave per round
                for (;;) {
                    unsigned v = __hip_atomic_load(myflags + E_OFF,
                                                   __ATOMIC_RELAXED, __HIP_MEMORY_SCOPE_AGENT);
                    if (v >= tgt) break;
                    __builtin_amdgcn_s_sleep(2);
                }
            }
        }

        // ---- h-part MFMAs; h read MALL-direct (fresh without any cache inv) ----
        f32x4 accH[4][2], accM[4][2];
#pragma unroll
        for (int mt = 0; mt < 4; ++mt)
#pragma unroll
            for (int nt = 0; nt < 2; ++nt) {
                accH[mt][nt] = f32x4{0.f, 0.f, 0.f, 0.f};
                accM[mt][nt] = f32x4{0.f, 0.f, 0.f, 0.f};
            }
#pragma unroll
        for (int sp = 0; sp < 5; ++sp) {
            int kt = wave + 4 * (s0 + sp);
#pragma unroll
            for (int mt = 0; mt < 4; ++mt) {
                int row = mt * 16 + l15;
                half8 Ah = ld_h8_mall(hcur + (unsigned)row * 640u + (kt * 32 - 320) + quad * 8);
#pragma unroll
                for (int nt = 0; nt < 2; ++nt) {
                    accH[mt][nt] = __builtin_amdgcn_mfma_f32_16x16x32_f16(Ah, Bh[sp][nt][0], accH[mt][nt], 0, 0, 0);
                    accM[mt][nt] = __builtin_amdgcn_mfma_f32_16x16x32_f16(Ah, Bh[sp][nt][1], accM[mt][nt], 0, 0, 0);
                }
            }
        }

        // ---- all-to-all K-merge through LDS ----
        __syncthreads();
#pragma unroll
        for (int mt = 0; mt < 4; ++mt)
#pragma unroll
            for (int nt = 0; nt < 2; ++nt)
                obox[wave][mt][nt][lane] = accH[mt][nt] + accM[mt][nt] * (1.0f / 2048.0f);
        __syncthreads();
        f32x4 z0 = obox[0][wave][0][lane] + obox[1][wave][0][lane]
                 + obox[2][wave][0][lane] + obox[3][wave][0][lane];
        f32x4 z1 = obox[0][wave][1][lane] + obox[1][wave][1][lane]
                 + obox[2][wave][1][lane] + obox[3][wave][1][lane];
        z0 += f32x4{z0p[0], z0p[1], z0p[2], z0p[3]};
        z1 += f32x4{z1p[0], z1p[1], z1p[2], z1p[3]};

        // ---- epilogue: this wave owns batch rows wave*16 .. wave*16+15 ----
#pragma unroll
        for (int r = 0; r < 4; ++r) {
            float zi = z0[r], zg = z1[r];
            float zf = __shfl_xor(z0[r], 8, 64);  // f gate lives 8 lanes over
            float zo = __shfl_xor(z1[r], 8, 64);
            if (l15 < 8) {
                float ig = 1.0f / (1.0f + __expf(-zi));
                float fg = 1.0f / (1.0f + __expf(-zf));
                float gg = tanhf(zg);
                float og = 1.0f / (1.0f + __expf(-zo));
                float c  = fg * cst[r] + ig * gg;
                cst[r] = c;
                float h = og * tanhf(c);
                if (t < Lr[r]) sum[r] += h;
                hstage[wave * 16 + quad * 4 + r][l15] = (f16)h;
            }
        }
        __syncthreads();   // hstage complete
        if (tid < 128) {
            // 128 threads publish 128 x 8B write-through stores (bypass L1/L2)
            int rr = tid >> 1, hf = tid & 1;
            unsigned long long v = *(const unsigned long long*)&hstage[rr][hf * 4];
            __hip_atomic_store(
                (unsigned long long*)(hnxt + (unsigned)rr * 640u + pc + hf * 4),
                v, __ATOMIC_RELAXED, __HIP_MEMORY_SCOPE_AGENT);
        }
        __syncthreads();   // drains all waves' stores (vmcnt(0)) before the flag store
        if (tid == 0)
            __hip_atomic_store(myflags + p, (unsigned)(t + 1),
                               __ATOMIC_RELAXED, __HIP_MEMORY_SCOPE_AGENT);
    }

    if (l15 < 8) {
#pragma unroll
        for (int r = 0; r < 4; ++r)
            out[(wave * 16 + quad * 4 + r) * 1200 + dir * 600 + pc + l15] =
                sum[r] * (1.0f / 512.0f);
    }
}

// ---------------- launcher ----------------
extern "C" void kernel_launch(void* const* d_in, const int* in_sizes, int n_in,
                              void* d_out, int out_size, void* d_ws, size_t ws_size,
                              hipStream_t stream) {
    const float* x   = (const float*)d_in[0];
    const int*   len = (const int*)  d_in[1];
    const float* Wf  = (const float*)d_in[3];
    const float* Uf  = (const float*)d_in[4];
    const float* bfv = (const float*)d_in[5];
    const float* Wb  = (const float*)d_in[6];
    const float* Ub  = (const float*)d_in[7];
    const float* bbv = (const float*)d_in[8];
    float* outp = (float*)d_out;

    char* w = (char*)d_ws;
    f16*      x16hp = (f16*)w;                         // 20,971,520 B
    f16*      x16lp = (f16*)(w + 20971520);            // 20,971,520 B
    f16*      bpkp  = (f16*)(w + 41943040);            // 18,432,000 B
    f16*      hbufp = (f16*)(w + 60375040);            //    327,680 B
    float*    xzp   = (float*)(w + 60702720);          // 150*13*64*32*4 = 15,974,400 B
    unsigned* flagp = (unsigned*)(w + 76677120);       //      1,024 B
    int*      maxtp = (int*)(w + 76678144);

    hipLaunchKernelGGL(lstm_prep, dim3(1024), dim3(256), 0, stream,
                       x, Wf, Uf, Wb, Ub, len,
                       x16hp, x16lp, bpkp, (unsigned*)hbufp, flagp, maxtp, outp);

    hipLaunchKernelGGL(lstm_main, dim3(GRID_MAIN), dim3(256), 0, stream,
                       x16hp, x16lp, bpkp, hbufp, xzp, flagp, maxtp, len, bfv, bbv, outp);
}